// Round 5
// baseline (724.936 us; speedup 1.0000x reference)
//
#include <hip/hip_runtime.h>
#include <hip/hip_bf16.h>
#include <math.h>

// ---------------------------------------------------------------------------
// GuoCapSAREncoder round 5:
//  - convcaps: re-gridded (512 blocks, 2 output rows each) + compact even/odd
//    column LDS layout + XOR sub-block swizzle -> conflict-free ds_read_b128.
//  - conv2: XOR sub-block swizzle on LDS staging -> all 32 banks.
//  - uhT in bf16 (halves routing-phase HBM/L2 traffic).
//  - conv1 unchanged (137 us, VALU-bound) -- next round's target.
// ---------------------------------------------------------------------------

#define EPSF 1e-8f

typedef __bf16 bf16x8 __attribute__((ext_vector_type(8)));
typedef __bf16 bf16x4 __attribute__((ext_vector_type(4)));
typedef float floatx4 __attribute__((ext_vector_type(4)));

// ---- weight transposes ----------------------------------------------------
__global__ __launch_bounds__(256) void k_t_w1(const float* __restrict__ w1, float* __restrict__ w1T) {
    int i = blockIdx.x * 256 + threadIdx.x;          // 128*81 = 10368
    if (i >= 10368) return;
    int oc = i / 81, k = i % 81;
    w1T[k * 128 + oc] = w1[i];
}

__global__ __launch_bounds__(256) void k_t_w2b(const float* __restrict__ w2, __bf16* __restrict__ w2b) {
    int j = blockIdx.x * 256 + threadIdx.x;          // 204800
    if (j >= 204800) return;
    int khw = j / 8192, r2 = j & 8191;
    int oc = r2 >> 7, ic = r2 & 127;
    w2b[j] = (__bf16)w2[(oc * 128 + ic) * 25 + khw];
}

__global__ __launch_bounds__(256) void k_t_wcb(const float* __restrict__ wc, __bf16* __restrict__ wcb) {
    int j = blockIdx.x * 256 + threadIdx.x;          // 524288
    if (j >= 524288) return;
    int khw = j / 8192, r2 = j & 8191;
    int oc = r2 >> 6, ic = r2 & 63;
    wcb[j] = (__bf16)wc[(oc * 64 + ic) * 64 + khw];
}

// ---- conv1 9x9 + ReLU + maxpool2 -> h1n NHWC bf16 [b][42][42][128] --------
__global__ __launch_bounds__(256, 2) void k_conv1_pool(const float* __restrict__ x,
                                                       const float* __restrict__ w1T,
                                                       const float* __restrict__ b1,
                                                       __bf16* __restrict__ h1n) {
    __shared__ float xs[936];                        // 10 rows x 92 + OOB pad
    int py = blockIdx.x, b = blockIdx.y;
    int t = threadIdx.x;
    int oc = t & 127, half = t >> 7;
    const float* xb = x + (size_t)b * 8464 + 2 * py * 92;
    for (int j = t; j < 920; j += 256) xs[j] = xb[j];
    float wr[81];
#pragma unroll
    for (int k = 0; k < 81; ++k) wr[k] = w1T[k * 128 + oc];   // coalesced
    float bias = b1[oc];
    __syncthreads();

    int base = half * 21;
    size_t rowbase = (((size_t)b * 42 + py) * 42) * 128 + oc;
#pragma unroll 1
    for (int jp = 0; jp < 11; ++jp) {
        int px0 = base + (jp < 10 ? 2 * jp : 20);
        int ix0 = 2 * px0;
        float a0 = bias, a1 = bias, a2 = bias, a3 = bias;
        float a4 = bias, a5 = bias, a6 = bias, a7 = bias;
#pragma unroll
        for (int r = 0; r < 10; ++r) {
            float cur[12];
            const float2* rp = (const float2*)&xs[r * 92 + ix0];
#pragma unroll
            for (int j6 = 0; j6 < 6; ++j6) ((float2*)cur)[j6] = rp[j6];
            if (r < 9) {
#pragma unroll
                for (int kw = 0; kw < 9; ++kw) {
                    float w0 = wr[r * 9 + kw];
                    a0 = fmaf(cur[kw], w0, a0);
                    a1 = fmaf(cur[kw + 1], w0, a1);
                    a2 = fmaf(cur[kw + 2], w0, a2);
                    a3 = fmaf(cur[kw + 3], w0, a3);
                }
            }
            if (r >= 1) {
#pragma unroll
                for (int kw = 0; kw < 9; ++kw) {
                    float wv = wr[(r - 1) * 9 + kw];
                    a4 = fmaf(cur[kw], wv, a4);
                    a5 = fmaf(cur[kw + 1], wv, a5);
                    a6 = fmaf(cur[kw + 2], wv, a6);
                    a7 = fmaf(cur[kw + 3], wv, a7);
                }
            }
        }
        float m0 = fmaxf(fmaxf(a0, a1), fmaxf(a4, a5));
        h1n[rowbase + (size_t)px0 * 128] = (__bf16)fmaxf(m0, 0.f);
        if (jp < 10) {
            float m1 = fmaxf(fmaxf(a2, a3), fmaxf(a6, a7));
            h1n[rowbase + (size_t)(px0 + 1) * 128] = (__bf16)fmaxf(m1, 0.f);
        }
    }
}

// ---- conv2 5x5 via MFMA: h1n NHWC bf16 -> h2n NHWC bf16 [b][38][38][64] ---
// LDS layout: element (pos, ic-subblock sb of 8) at byte (pos*8 + (sb^(pos&7)))*16
// -> all 32 banks, 8 dwords/bank per ds_read_b128 wave (conflict-free).
__global__ __launch_bounds__(256, 2) void k_conv2(const __bf16* __restrict__ h1n,
                                                  const __bf16* __restrict__ w2b,
                                                  const float* __restrict__ b2,
                                                  __bf16* __restrict__ h2n) {
    __shared__ __bf16 ins[8 * 42 * 64];              // 43008 B
    int g = blockIdx.x, b = blockIdx.y;              // g in [0,10)
    int oh0 = g * 4;
    int t = threadIdx.x;
    int lane = t & 63, w = t >> 6;
    int wm = w & 1, wn = w >> 1;
    int cc = lane & 15, q = lane >> 4;

    int posN[5], rv[5], cv[5], posv[5];
#pragma unroll
    for (int nt = 0; nt < 5; ++nt) {
        int p = wn * 80 + nt * 16 + cc;
        int pv = p < 152 ? p : 151;
        int r = pv / 38, c = pv - r * 38;
        posv[nt] = p; rv[nt] = r; cv[nt] = c;
        posN[nt] = r * 42 + c;                       // slab position index
    }
    floatx4 acc[2][5];
#pragma unroll
    for (int mt = 0; mt < 2; ++mt)
#pragma unroll
        for (int nt = 0; nt < 5; ++nt) acc[mt][nt] = (floatx4){0.f, 0.f, 0.f, 0.f};

    int ocA0 = wm * 32 + cc;
    for (int ic0 = 0; ic0 < 128; ic0 += 64) {
        __syncthreads();
        for (int j = t; j < 2688; j += 256) {        // 8 rows x 42 x 8 sb
            int lr = j / 336, rem = j - lr * 336;
            int ix = rem >> 3, sb = rem & 7;
            int rg = oh0 + lr; if (rg > 41) rg = 41;
            const uint4* src = (const uint4*)(h1n + ((((size_t)b * 42 + rg) * 42 + ix) * 128 + ic0 + sb * 8));
            int pos = lr * 42 + ix;
            *(uint4*)((char*)ins + (size_t)(pos * 8 + (sb ^ (pos & 7))) * 16) = *src;
        }
        __syncthreads();
#pragma unroll
        for (int khw = 0; khw < 25; ++khw) {
            int kh = khw / 5, kw = khw - kh * 5;
            int dpos = kh * 42 + kw;
#pragma unroll
            for (int ks = 0; ks < 2; ++ks) {
                bf16x8 a0 = *(const bf16x8*)(w2b + (size_t)(khw * 64 + ocA0) * 128 + ic0 + ks * 32 + q * 8);
                bf16x8 a1 = *(const bf16x8*)(w2b + (size_t)(khw * 64 + ocA0 + 16) * 128 + ic0 + ks * 32 + q * 8);
                int sbr = ks * 4 + q;
#pragma unroll
                for (int nt = 0; nt < 5; ++nt) {
                    int posr = posN[nt] + dpos;
                    bf16x8 bfr = *(const bf16x8*)((char*)ins + (size_t)(posr * 8 + (sbr ^ (posr & 7))) * 16);
                    acc[0][nt] = __builtin_amdgcn_mfma_f32_16x16x32_bf16(a0, bfr, acc[0][nt], 0, 0, 0);
                    acc[1][nt] = __builtin_amdgcn_mfma_f32_16x16x32_bf16(a1, bfr, acc[1][nt], 0, 0, 0);
                }
            }
        }
    }
#pragma unroll
    for (int mt = 0; mt < 2; ++mt) {
        int oc0 = wm * 32 + mt * 16 + q * 4;
        float4 bv = *(const float4*)(b2 + oc0);
#pragma unroll
        for (int nt = 0; nt < 5; ++nt) {
            int oh = oh0 + rv[nt];
            if (posv[nt] < 152 && oh < 38) {
                bf16x4 pk;
                pk.x = (__bf16)(acc[mt][nt][0] + bv.x);
                pk.y = (__bf16)(acc[mt][nt][1] + bv.y);
                pk.z = (__bf16)(acc[mt][nt][2] + bv.z);
                pk.w = (__bf16)(acc[mt][nt][3] + bv.w);
                *(bf16x4*)(h2n + ((((size_t)b * 38 + oh) * 38 + cv[nt]) * 64 + oc0)) = pk;
            }
        }
    }
}

// ---- caps conv 8x8 s2 via MFMA: h2n NHWC bf16 -> hcn NHWC fp32 ------------
// Block = 2 output rows (32 pos) x 128 oc; grid 8 x 64 = 512 blocks.
// LDS: compact even/odd column layout kills the stride-2 penalty:
//   element (row r, col c, ic l): par=c&1, ch=c>>1, s=l>>3
//   byte = (((r*2+par)*19 + ch)*4 + (s ^ (ch&3))) * 16     (24320 B / chunk)
// Read (col=2*cc+kw): ch = cc + (kw>>1) -> consecutive per lane, conflict-free.
__global__ __launch_bounds__(256, 4) void k_convcaps(const __bf16* __restrict__ h2n,
                                                     const __bf16* __restrict__ wcb,
                                                     const float* __restrict__ bc,
                                                     float* __restrict__ hcn) {
    __shared__ __bf16 ins[12160];                    // 24320 B
    int g = blockIdx.x, b = blockIdx.y;              // g in [0,8)
    int t = threadIdx.x;
    int lane = t & 63, w = t >> 6;
    int cc = lane & 15, q = lane >> 4;

    floatx4 acc[2][2];                               // [mt][nt]
#pragma unroll
    for (int mt = 0; mt < 2; ++mt)
#pragma unroll
        for (int nt = 0; nt < 2; ++nt) acc[mt][nt] = (floatx4){0.f, 0.f, 0.f, 0.f};

    int ocA = w * 32 + cc;
    for (int ic0 = 0; ic0 < 64; ic0 += 32) {
        __syncthreads();
        for (int j = t; j < 1520; j += 256) {        // 10 rows x 38 cols x 4 s
            int r = j / 152, rem = j - r * 152;
            int c = rem >> 2, s = rem & 3;
            const uint4* src = (const uint4*)(h2n + ((((size_t)b * 38 + 4 * g + r) * 38 + c) * 64 + ic0 + s * 8));
            int X = (r * 2 + (c & 1)) * 19 + (c >> 1);
            *(uint4*)((char*)ins + (size_t)(X * 4 + (s ^ ((c >> 1) & 3))) * 16) = *src;
        }
        __syncthreads();
#pragma unroll
        for (int khw = 0; khw < 64; ++khw) {
            int kh = khw >> 3, kw = khw & 7;
            bf16x8 a0 = *(const bf16x8*)(wcb + (size_t)(khw * 128 + ocA) * 64 + ic0 + q * 8);
            bf16x8 a1 = *(const bf16x8*)(wcb + (size_t)(khw * 128 + ocA + 16) * 64 + ic0 + q * 8);
            int par = kw & 1, k2 = kw >> 1;
#pragma unroll
            for (int nt = 0; nt < 2; ++nt) {
                int r = 2 * nt + kh;
                int ch = cc + k2;
                int X = (r * 2 + par) * 19 + ch;
                bf16x8 bfr = *(const bf16x8*)((char*)ins + (size_t)(X * 4 + (q ^ (ch & 3))) * 16);
                acc[0][nt] = __builtin_amdgcn_mfma_f32_16x16x32_bf16(a0, bfr, acc[0][nt], 0, 0, 0);
                acc[1][nt] = __builtin_amdgcn_mfma_f32_16x16x32_bf16(a1, bfr, acc[1][nt], 0, 0, 0);
            }
        }
    }
#pragma unroll
    for (int mt = 0; mt < 2; ++mt) {
        int oc0 = w * 32 + mt * 16 + q * 4;
        float4 bv = *(const float4*)(bc + oc0);
#pragma unroll
        for (int nt = 0; nt < 2; ++nt) {
            int oh = 2 * g + nt, ow = cc;
            float4 st;
            st.x = acc[mt][nt][0] + bv.x;
            st.y = acc[mt][nt][1] + bv.y;
            st.z = acc[mt][nt][2] + bv.z;
            st.w = acc[mt][nt][3] + bv.w;
            *(float4*)(hcn + (((size_t)b * 256 + oh * 16 + ow) * 128 + oc0)) = st;
        }
    }
}

// ---- primary-capsule reorder + squash: hcn NHWC -> u:[64,1024,32] ---------
__global__ __launch_bounds__(256) void k_squash(const float* __restrict__ hcn,
                                                float* __restrict__ u) {
    int b = blockIdx.x, capg = blockIdx.y;           // capg in [0,128)
    int t = threadIdx.x;
    int capl = t >> 5, i = t & 31;
    int cap = capg * 8 + capl;
    int ct = cap >> 8, rem = cap & 255;              // rem = y*16+x
    float val = hcn[((size_t)b * 256 + rem) * 128 + ct * 32 + i];
    float s = val * val;
#pragma unroll
    for (int off = 1; off < 32; off <<= 1) s += __shfl_xor(s, off, 64);
    float scale = (s / (1.f + s)) / sqrtf(s + EPSF);
    u[((size_t)b * 1024 + cap) * 32 + i] = val * scale;
}

// ---- u_hat: u:[64,1024,32] Wr:[1024,10,16,32] -> uhT bf16 [b][t][o][p] ----
__global__ __launch_bounds__(256) void k_uhat(const float* __restrict__ u,
                                              const float* __restrict__ Wr,
                                              __bf16* __restrict__ uhT) {
    int pt = blockIdx.x;   // 16 tiles of 64 p
    int ts = blockIdx.y;   // 10
    int bz = blockIdx.z;   // 4 groups of 16 b
    int t = threadIdx.x;
    int p = pt * 64 + (t & 63);
    int q = t >> 6;
    for (int b = bz * 16 + q; b < bz * 16 + 16; b += 4) {
        float4 uu[8];
        const float4* up = (const float4*)(u + ((size_t)b * 1024 + p) * 32);
#pragma unroll
        for (int j = 0; j < 8; ++j) uu[j] = up[j];
#pragma unroll
        for (int o = 0; o < 16; ++o) {
            const float4* wp = (const float4*)(Wr + (((size_t)p * 10 + ts) * 16 + o) * 32);
            float4 a = {0.f, 0.f, 0.f, 0.f};
#pragma unroll
            for (int j = 0; j < 8; ++j) {
                float4 w4 = wp[j];
                a.x = fmaf(uu[j].x, w4.x, a.x);
                a.y = fmaf(uu[j].y, w4.y, a.y);
                a.z = fmaf(uu[j].z, w4.z, a.z);
                a.w = fmaf(uu[j].w, w4.w, a.w);
            }
            uhT[(((size_t)b * 10 + ts) * 16 + o) * 1024 + p] = (__bf16)((a.x + a.y) + (a.z + a.w));
        }
    }
}

// ---- routing: s = sum_p softmax(bl)_pt * u_hat ; v = squash(s) ------------
__global__ __launch_bounds__(256) void k_route_s(const __bf16* __restrict__ uhT,
                                                 const float* __restrict__ bl,
                                                 float* __restrict__ vout,
                                                 float* __restrict__ out,
                                                 int first, int last) {
    __shared__ float sred[4][16];
    int b = blockIdx.x, tt = blockIdx.y;
    int t = threadIdx.x;
    float acc[16];
#pragma unroll
    for (int o = 0; o < 16; ++o) acc[o] = 0.f;
    const float* blb = bl + b * 10240;
    const __bf16* uhb = uhT + ((size_t)b * 10 + tt) * 16384;
    for (int p = t; p < 1024; p += 256) {
        float c;
        if (first) {
            c = 0.1f;
        } else {
            float den = 0.f, et = 0.f;
#pragma unroll
            for (int tp = 0; tp < 10; ++tp) {
                float e = expf(blb[tp * 1024 + p]);
                den += e;
                if (tp == tt) et = e;
            }
            c = et / den;
        }
#pragma unroll
        for (int o = 0; o < 16; ++o)
            acc[o] = fmaf(c, (float)uhb[o * 1024 + p], acc[o]);
    }
    int lane = t & 63, wid = t >> 6;
#pragma unroll
    for (int o = 0; o < 16; ++o) {
        float v = acc[o];
#pragma unroll
        for (int off = 32; off >= 1; off >>= 1) v += __shfl_xor(v, off, 64);
        if (lane == 0) sred[wid][o] = v;
    }
    __syncthreads();
    if (t < 16) {
        float s = (sred[0][t] + sred[1][t]) + (sred[2][t] + sred[3][t]);
        float n2 = s * s;
#pragma unroll
        for (int off = 1; off < 16; off <<= 1) n2 += __shfl_xor(n2, off, 16);
        float scale = (n2 / (1.f + n2)) / sqrtf(n2 + EPSF);
        vout[(b * 10 + tt) * 16 + t] = s * scale;
        if (last && t == 0) {
            float sv2 = n2 * scale * scale;
            out[b * 10 + tt] = sqrtf(sv2 + EPSF);
        }
    }
}

// ---- routing: bl (+)= sum_o u_hat * v -------------------------------------
__global__ __launch_bounds__(256) void k_route_b(const __bf16* __restrict__ uhT,
                                                 const float* __restrict__ vv,
                                                 float* __restrict__ bl,
                                                 int first) {
    __shared__ float vs[16];
    int b = blockIdx.x, tt = blockIdx.y;
    int t = threadIdx.x;
    if (t < 16) vs[t] = vv[(b * 10 + tt) * 16 + t];
    __syncthreads();
    const __bf16* uhb = uhT + ((size_t)b * 10 + tt) * 16384;
    float* blb = bl + (b * 10 + tt) * 1024;
    for (int p = t; p < 1024; p += 256) {
        float d = 0.f;
#pragma unroll
        for (int o = 0; o < 16; ++o) d = fmaf((float)uhb[o * 1024 + p], vs[o], d);
        blb[p] = first ? d : (blb[p] + d);
    }
}

// ---------------------------------------------------------------------------
extern "C" void kernel_launch(void* const* d_in, const int* in_sizes, int n_in,
                              void* d_out, int out_size, void* d_ws, size_t ws_size,
                              hipStream_t stream) {
    const float* x  = (const float*)d_in[0];
    const float* w1 = (const float*)d_in[1];
    const float* b1 = (const float*)d_in[2];
    const float* w2 = (const float*)d_in[3];
    const float* b2 = (const float*)d_in[4];
    const float* wc = (const float*)d_in[5];
    const float* bc = (const float*)d_in[6];
    const float* Wr = (const float*)d_in[7];
    float* out = (float*)d_out;
    float* ws  = (float*)d_ws;

    // workspace layout (float offsets)
    __bf16* w2b = (__bf16*)(ws);                  // 204800 bf16 = 102400 f
    __bf16* wcb = (__bf16*)(ws + 102400);         // 524288 bf16 = 262144 f
    float*  w1T = ws + 364544;                    // 10368 f (pad to 10496)
    __bf16* h1n = (__bf16*)(ws + 375040);         // 14450688 bf16 = 7225344 f
    __bf16* h2n = (__bf16*)(ws + 7600384);        // 5914624 bf16 = 2957312 f
    float*  hcn = ws + 10557696;                  // 2097152 f
    float*  u   = ws + 12654848;                  // 2097152 f
    float*  bl  = ws + 14752000;                  // 655360 f
    float*  vv  = ws + 15407360;                  // 10240 f -> 15417600 f (61.7 MB)
    __bf16* uhT = (__bf16*)(ws + 375040);         // 10485760 bf16, overlays h1n (dead)

    k_t_w1<<<41, 256, 0, stream>>>(w1, w1T);
    k_t_w2b<<<800, 256, 0, stream>>>(w2, w2b);
    k_t_wcb<<<2048, 256, 0, stream>>>(wc, wcb);
    k_conv1_pool<<<dim3(42, 64), 256, 0, stream>>>(x, w1T, b1, h1n);
    k_conv2<<<dim3(10, 64), 256, 0, stream>>>(h1n, w2b, b2, h2n);
    k_convcaps<<<dim3(8, 64), 256, 0, stream>>>(h2n, wcb, bc, hcn);
    k_squash<<<dim3(64, 128), 256, 0, stream>>>(hcn, u);
    k_uhat<<<dim3(16, 10, 4), 256, 0, stream>>>(u, Wr, uhT);
    k_route_s<<<dim3(64, 10), 256, 0, stream>>>(uhT, bl, vv, out, 1, 0);
    k_route_b<<<dim3(64, 10), 256, 0, stream>>>(uhT, vv, bl, 1);
    k_route_s<<<dim3(64, 10), 256, 0, stream>>>(uhT, bl, vv, out, 0, 0);
    k_route_b<<<dim3(64, 10), 256, 0, stream>>>(uhT, vv, bl, 0);
    k_route_s<<<dim3(64, 10), 256, 0, stream>>>(uhT, bl, vv, out, 0, 1);
}

// Round 6
// 554.321 us; speedup vs baseline: 1.3078x; 1.3078x over previous
//
#include <hip/hip_runtime.h>
#include <hip/hip_bf16.h>
#include <math.h>

// ---------------------------------------------------------------------------
// GuoCapSAREncoder round 6: conflict-free LDS via PADDED PITCH (compile-time
// offsets) instead of per-access XOR swizzle (which blew the 128-VGPR cap and
// spilled -> 220 MB/dispatch scratch traffic in round 5).
//  - conv2: pitch 136 B/pos (34 dwords = 2 mod 32 banks) -> uniform 8 dw/bank.
//  - convcaps: even/odd col layout, pitch 72 B (18 dwords = 2 mod 32).
//  - all read offsets = per-lane base VGPR + ds_read immediate.
// ---------------------------------------------------------------------------

#define EPSF 1e-8f

typedef __bf16 bf16x8 __attribute__((ext_vector_type(8)));
typedef __bf16 bf16x4 __attribute__((ext_vector_type(4)));
typedef float floatx4 __attribute__((ext_vector_type(4)));

// ---- weight transposes ----------------------------------------------------
__global__ __launch_bounds__(256) void k_t_w1(const float* __restrict__ w1, float* __restrict__ w1T) {
    int i = blockIdx.x * 256 + threadIdx.x;          // 128*81 = 10368
    if (i >= 10368) return;
    int oc = i / 81, k = i % 81;
    w1T[k * 128 + oc] = w1[i];
}

__global__ __launch_bounds__(256) void k_t_w2b(const float* __restrict__ w2, __bf16* __restrict__ w2b) {
    int j = blockIdx.x * 256 + threadIdx.x;          // 204800
    if (j >= 204800) return;
    int khw = j / 8192, r2 = j & 8191;
    int oc = r2 >> 7, ic = r2 & 127;
    w2b[j] = (__bf16)w2[(oc * 128 + ic) * 25 + khw];
}

__global__ __launch_bounds__(256) void k_t_wcb(const float* __restrict__ wc, __bf16* __restrict__ wcb) {
    int j = blockIdx.x * 256 + threadIdx.x;          // 524288
    if (j >= 524288) return;
    int khw = j / 8192, r2 = j & 8191;
    int oc = r2 >> 6, ic = r2 & 63;
    wcb[j] = (__bf16)wc[(oc * 64 + ic) * 64 + khw];
}

// ---- conv1 9x9 + ReLU + maxpool2 -> h1n NHWC bf16 [b][42][42][128] --------
__global__ __launch_bounds__(256, 2) void k_conv1_pool(const float* __restrict__ x,
                                                       const float* __restrict__ w1T,
                                                       const float* __restrict__ b1,
                                                       __bf16* __restrict__ h1n) {
    __shared__ float xs[936];                        // 10 rows x 92 + OOB pad
    int py = blockIdx.x, b = blockIdx.y;
    int t = threadIdx.x;
    int oc = t & 127, half = t >> 7;
    const float* xb = x + (size_t)b * 8464 + 2 * py * 92;
    for (int j = t; j < 920; j += 256) xs[j] = xb[j];
    float wr[81];
#pragma unroll
    for (int k = 0; k < 81; ++k) wr[k] = w1T[k * 128 + oc];   // coalesced
    float bias = b1[oc];
    __syncthreads();

    int base = half * 21;
    size_t rowbase = (((size_t)b * 42 + py) * 42) * 128 + oc;
#pragma unroll 1
    for (int jp = 0; jp < 11; ++jp) {
        int px0 = base + (jp < 10 ? 2 * jp : 20);
        int ix0 = 2 * px0;
        float a0 = bias, a1 = bias, a2 = bias, a3 = bias;
        float a4 = bias, a5 = bias, a6 = bias, a7 = bias;
#pragma unroll
        for (int r = 0; r < 10; ++r) {
            float cur[12];
            const float2* rp = (const float2*)&xs[r * 92 + ix0];
#pragma unroll
            for (int j6 = 0; j6 < 6; ++j6) ((float2*)cur)[j6] = rp[j6];
            if (r < 9) {
#pragma unroll
                for (int kw = 0; kw < 9; ++kw) {
                    float w0 = wr[r * 9 + kw];
                    a0 = fmaf(cur[kw], w0, a0);
                    a1 = fmaf(cur[kw + 1], w0, a1);
                    a2 = fmaf(cur[kw + 2], w0, a2);
                    a3 = fmaf(cur[kw + 3], w0, a3);
                }
            }
            if (r >= 1) {
#pragma unroll
                for (int kw = 0; kw < 9; ++kw) {
                    float wv = wr[(r - 1) * 9 + kw];
                    a4 = fmaf(cur[kw], wv, a4);
                    a5 = fmaf(cur[kw + 1], wv, a5);
                    a6 = fmaf(cur[kw + 2], wv, a6);
                    a7 = fmaf(cur[kw + 3], wv, a7);
                }
            }
        }
        float m0 = fmaxf(fmaxf(a0, a1), fmaxf(a4, a5));
        h1n[rowbase + (size_t)px0 * 128] = (__bf16)fmaxf(m0, 0.f);
        if (jp < 10) {
            float m1 = fmaxf(fmaxf(a2, a3), fmaxf(a6, a7));
            h1n[rowbase + (size_t)(px0 + 1) * 128] = (__bf16)fmaxf(m1, 0.f);
        }
    }
}

// ---- conv2 5x5 via MFMA: h1n NHWC bf16 -> h2n NHWC bf16 [b][38][38][64] ---
// LDS: (pos, sb) at byte pos*136 + sb*16 (pitch 34 dwords = 2 mod 32 banks).
// Reads: per-lane base + compile-time immediate -> no dynamic addr math.
__global__ __launch_bounds__(256, 2) void k_conv2(const __bf16* __restrict__ h1n,
                                                  const __bf16* __restrict__ w2b,
                                                  const float* __restrict__ b2,
                                                  __bf16* __restrict__ h2n) {
    __shared__ __bf16 ins[22848];                    // 336 pos * 136 B = 45696 B
    int g = blockIdx.x, b = blockIdx.y;              // g in [0,10)
    int oh0 = g * 4;
    int t = threadIdx.x;
    int lane = t & 63, w = t >> 6;
    int wm = w & 1, wn = w >> 1;
    int cc = lane & 15, q = lane >> 4;

    int baseN[5], posv[5];
#pragma unroll
    for (int nt = 0; nt < 5; ++nt) {
        int p = wn * 80 + nt * 16 + cc;
        int pv = p < 152 ? p : 151;
        int r = pv / 38, c = pv - r * 38;
        posv[nt] = p;
        baseN[nt] = (r * 42 + c) * 136 + q * 16;     // byte base in padded slab
    }
    floatx4 acc[2][5];
#pragma unroll
    for (int mt = 0; mt < 2; ++mt)
#pragma unroll
        for (int nt = 0; nt < 5; ++nt) acc[mt][nt] = (floatx4){0.f, 0.f, 0.f, 0.f};

    int ocA0 = wm * 32 + cc;
    for (int ic0 = 0; ic0 < 128; ic0 += 64) {
        __syncthreads();
        for (int j = t; j < 2688; j += 256) {        // 8 rows x 42 x 8 sb
            int lr = j / 336, rem = j - lr * 336;
            int ix = rem >> 3, sb = rem & 7;
            int rg = oh0 + lr; if (rg > 41) rg = 41;
            const uint4* src = (const uint4*)(h1n + ((((size_t)b * 42 + rg) * 42 + ix) * 128 + ic0 + sb * 8));
            int pos = lr * 42 + ix;
            *(uint4*)((char*)ins + (size_t)pos * 136 + sb * 16) = *src;
        }
        __syncthreads();
#pragma unroll
        for (int khw = 0; khw < 25; ++khw) {
            int kh = khw / 5, kw = khw - kh * 5;
            int doff = (kh * 42 + kw) * 136;         // compile-time per khw
#pragma unroll
            for (int ks = 0; ks < 2; ++ks) {
                bf16x8 a0 = *(const bf16x8*)(w2b + (size_t)(khw * 64 + ocA0) * 128 + ic0 + ks * 32 + q * 8);
                bf16x8 a1 = *(const bf16x8*)(w2b + (size_t)(khw * 64 + ocA0 + 16) * 128 + ic0 + ks * 32 + q * 8);
#pragma unroll
                for (int nt = 0; nt < 5; ++nt) {
                    bf16x8 bfr = *(const bf16x8*)((char*)ins + baseN[nt] + doff + ks * 64);
                    acc[0][nt] = __builtin_amdgcn_mfma_f32_16x16x32_bf16(a0, bfr, acc[0][nt], 0, 0, 0);
                    acc[1][nt] = __builtin_amdgcn_mfma_f32_16x16x32_bf16(a1, bfr, acc[1][nt], 0, 0, 0);
                }
            }
        }
    }
#pragma unroll
    for (int mt = 0; mt < 2; ++mt) {
        int oc0 = wm * 32 + mt * 16 + q * 4;
        float4 bv = *(const float4*)(b2 + oc0);
#pragma unroll
        for (int nt = 0; nt < 5; ++nt) {
            int p = posv[nt];
            if (p < 152) {
                int r = p / 38, c = p - r * 38;
                int oh = oh0 + r;
                if (oh < 38) {
                    bf16x4 pk;
                    pk.x = (__bf16)(acc[mt][nt][0] + bv.x);
                    pk.y = (__bf16)(acc[mt][nt][1] + bv.y);
                    pk.z = (__bf16)(acc[mt][nt][2] + bv.z);
                    pk.w = (__bf16)(acc[mt][nt][3] + bv.w);
                    *(bf16x4*)(h2n + ((((size_t)b * 38 + oh) * 38 + c) * 64 + oc0)) = pk;
                }
            }
        }
    }
}

// ---- caps conv 8x8 s2 via MFMA: h2n NHWC bf16 -> hcn NHWC fp32 ------------
// Block = 2 output rows x 128 oc; grid 8 x 64.
// LDS: even/odd col layout, X=(r*2+(c&1))*19+(c>>1), byte = X*72 + s*16
// (pitch 18 dwords = 2 mod 32 banks -> uniform). Reads: base + immediate.
__global__ __launch_bounds__(256, 2) void k_convcaps(const __bf16* __restrict__ h2n,
                                                     const __bf16* __restrict__ wcb,
                                                     const float* __restrict__ bc,
                                                     float* __restrict__ hcn) {
    __shared__ __bf16 ins[13680];                    // 380 * 72 B = 27360 B
    int g = blockIdx.x, b = blockIdx.y;              // g in [0,8)
    int t = threadIdx.x;
    int lane = t & 63, w = t >> 6;
    int cc = lane & 15, q = lane >> 4;

    floatx4 acc[2][2];                               // [mt][nt]
#pragma unroll
    for (int mt = 0; mt < 2; ++mt)
#pragma unroll
        for (int nt = 0; nt < 2; ++nt) acc[mt][nt] = (floatx4){0.f, 0.f, 0.f, 0.f};

    int ocA = w * 32 + cc;
    int rbase = cc * 72 + q * 16;                    // per-lane LDS byte base
    for (int ic0 = 0; ic0 < 64; ic0 += 32) {
        __syncthreads();
        for (int j = t; j < 1520; j += 256) {        // 10 rows x 38 cols x 4 s
            int r = j / 152, rem = j - r * 152;
            int c = rem >> 2, s = rem & 3;
            const uint4* src = (const uint4*)(h2n + ((((size_t)b * 38 + 4 * g + r) * 38 + c) * 64 + ic0 + s * 8));
            int X = (r * 2 + (c & 1)) * 19 + (c >> 1);
            *(uint4*)((char*)ins + X * 72 + s * 16) = *src;
        }
        __syncthreads();
#pragma unroll
        for (int khw = 0; khw < 64; ++khw) {
            int kh = khw >> 3, kw = khw & 7;
            int par = kw & 1, k2 = kw >> 1;
            bf16x8 a0 = *(const bf16x8*)(wcb + (size_t)(khw * 128 + ocA) * 64 + ic0 + q * 8);
            bf16x8 a1 = *(const bf16x8*)(wcb + (size_t)(khw * 128 + ocA + 16) * 64 + ic0 + q * 8);
#pragma unroll
            for (int nt = 0; nt < 2; ++nt) {
                int doff = (((2 * nt + kh) * 2 + par) * 19 + k2) * 72;  // imm
                bf16x8 bfr = *(const bf16x8*)((char*)ins + rbase + doff);
                acc[0][nt] = __builtin_amdgcn_mfma_f32_16x16x32_bf16(a0, bfr, acc[0][nt], 0, 0, 0);
                acc[1][nt] = __builtin_amdgcn_mfma_f32_16x16x32_bf16(a1, bfr, acc[1][nt], 0, 0, 0);
            }
        }
    }
#pragma unroll
    for (int mt = 0; mt < 2; ++mt) {
        int oc0 = w * 32 + mt * 16 + q * 4;
        float4 bv = *(const float4*)(bc + oc0);
#pragma unroll
        for (int nt = 0; nt < 2; ++nt) {
            int oh = 2 * g + nt, ow = cc;
            float4 st;
            st.x = acc[mt][nt][0] + bv.x;
            st.y = acc[mt][nt][1] + bv.y;
            st.z = acc[mt][nt][2] + bv.z;
            st.w = acc[mt][nt][3] + bv.w;
            *(float4*)(hcn + (((size_t)b * 256 + oh * 16 + ow) * 128 + oc0)) = st;
        }
    }
}

// ---- primary-capsule reorder + squash: hcn NHWC -> u:[64,1024,32] ---------
__global__ __launch_bounds__(256) void k_squash(const float* __restrict__ hcn,
                                                float* __restrict__ u) {
    int b = blockIdx.x, capg = blockIdx.y;           // capg in [0,128)
    int t = threadIdx.x;
    int capl = t >> 5, i = t & 31;
    int cap = capg * 8 + capl;
    int ct = cap >> 8, rem = cap & 255;              // rem = y*16+x
    float val = hcn[((size_t)b * 256 + rem) * 128 + ct * 32 + i];
    float s = val * val;
#pragma unroll
    for (int off = 1; off < 32; off <<= 1) s += __shfl_xor(s, off, 64);
    float scale = (s / (1.f + s)) / sqrtf(s + EPSF);
    u[((size_t)b * 1024 + cap) * 32 + i] = val * scale;
}

// ---- u_hat: u:[64,1024,32] Wr:[1024,10,16,32] -> uhT bf16 [b][t][o][p] ----
__global__ __launch_bounds__(256) void k_uhat(const float* __restrict__ u,
                                              const float* __restrict__ Wr,
                                              __bf16* __restrict__ uhT) {
    int pt = blockIdx.x;   // 16 tiles of 64 p
    int ts = blockIdx.y;   // 10
    int bz = blockIdx.z;   // 4 groups of 16 b
    int t = threadIdx.x;
    int p = pt * 64 + (t & 63);
    int q = t >> 6;
    for (int b = bz * 16 + q; b < bz * 16 + 16; b += 4) {
        float4 uu[8];
        const float4* up = (const float4*)(u + ((size_t)b * 1024 + p) * 32);
#pragma unroll
        for (int j = 0; j < 8; ++j) uu[j] = up[j];
#pragma unroll
        for (int o = 0; o < 16; ++o) {
            const float4* wp = (const float4*)(Wr + (((size_t)p * 10 + ts) * 16 + o) * 32);
            float4 a = {0.f, 0.f, 0.f, 0.f};
#pragma unroll
            for (int j = 0; j < 8; ++j) {
                float4 w4 = wp[j];
                a.x = fmaf(uu[j].x, w4.x, a.x);
                a.y = fmaf(uu[j].y, w4.y, a.y);
                a.z = fmaf(uu[j].z, w4.z, a.z);
                a.w = fmaf(uu[j].w, w4.w, a.w);
            }
            uhT[(((size_t)b * 10 + ts) * 16 + o) * 1024 + p] = (__bf16)((a.x + a.y) + (a.z + a.w));
        }
    }
}

// ---- routing: s = sum_p softmax(bl)_pt * u_hat ; v = squash(s) ------------
__global__ __launch_bounds__(256) void k_route_s(const __bf16* __restrict__ uhT,
                                                 const float* __restrict__ bl,
                                                 float* __restrict__ vout,
                                                 float* __restrict__ out,
                                                 int first, int last) {
    __shared__ float sred[4][16];
    int b = blockIdx.x, tt = blockIdx.y;
    int t = threadIdx.x;
    float acc[16];
#pragma unroll
    for (int o = 0; o < 16; ++o) acc[o] = 0.f;
    const float* blb = bl + b * 10240;
    const __bf16* uhb = uhT + ((size_t)b * 10 + tt) * 16384;
    for (int p = t; p < 1024; p += 256) {
        float c;
        if (first) {
            c = 0.1f;
        } else {
            float den = 0.f, et = 0.f;
#pragma unroll
            for (int tp = 0; tp < 10; ++tp) {
                float e = expf(blb[tp * 1024 + p]);
                den += e;
                if (tp == tt) et = e;
            }
            c = et / den;
        }
#pragma unroll
        for (int o = 0; o < 16; ++o)
            acc[o] = fmaf(c, (float)uhb[o * 1024 + p], acc[o]);
    }
    int lane = t & 63, wid = t >> 6;
#pragma unroll
    for (int o = 0; o < 16; ++o) {
        float v = acc[o];
#pragma unroll
        for (int off = 32; off >= 1; off >>= 1) v += __shfl_xor(v, off, 64);
        if (lane == 0) sred[wid][o] = v;
    }
    __syncthreads();
    if (t < 16) {
        float s = (sred[0][t] + sred[1][t]) + (sred[2][t] + sred[3][t]);
        float n2 = s * s;
#pragma unroll
        for (int off = 1; off < 16; off <<= 1) n2 += __shfl_xor(n2, off, 16);
        float scale = (n2 / (1.f + n2)) / sqrtf(n2 + EPSF);
        vout[(b * 10 + tt) * 16 + t] = s * scale;
        if (last && t == 0) {
            float sv2 = n2 * scale * scale;
            out[b * 10 + tt] = sqrtf(sv2 + EPSF);
        }
    }
}

// ---- routing: bl (+)= sum_o u_hat * v -------------------------------------
__global__ __launch_bounds__(256) void k_route_b(const __bf16* __restrict__ uhT,
                                                 const float* __restrict__ vv,
                                                 float* __restrict__ bl,
                                                 int first) {
    __shared__ float vs[16];
    int b = blockIdx.x, tt = blockIdx.y;
    int t = threadIdx.x;
    if (t < 16) vs[t] = vv[(b * 10 + tt) * 16 + t];
    __syncthreads();
    const __bf16* uhb = uhT + ((size_t)b * 10 + tt) * 16384;
    float* blb = bl + (b * 10 + tt) * 1024;
    for (int p = t; p < 1024; p += 256) {
        float d = 0.f;
#pragma unroll
        for (int o = 0; o < 16; ++o) d = fmaf((float)uhb[o * 1024 + p], vs[o], d);
        blb[p] = first ? d : (blb[p] + d);
    }
}

// ---------------------------------------------------------------------------
extern "C" void kernel_launch(void* const* d_in, const int* in_sizes, int n_in,
                              void* d_out, int out_size, void* d_ws, size_t ws_size,
                              hipStream_t stream) {
    const float* x  = (const float*)d_in[0];
    const float* w1 = (const float*)d_in[1];
    const float* b1 = (const float*)d_in[2];
    const float* w2 = (const float*)d_in[3];
    const float* b2 = (const float*)d_in[4];
    const float* wc = (const float*)d_in[5];
    const float* bc = (const float*)d_in[6];
    const float* Wr = (const float*)d_in[7];
    float* out = (float*)d_out;
    float* ws  = (float*)d_ws;

    // workspace layout (float offsets)
    __bf16* w2b = (__bf16*)(ws);                  // 204800 bf16 = 102400 f
    __bf16* wcb = (__bf16*)(ws + 102400);         // 524288 bf16 = 262144 f
    float*  w1T = ws + 364544;                    // 10368 f (pad to 10496)
    __bf16* h1n = (__bf16*)(ws + 375040);         // 14450688 bf16 = 7225344 f
    __bf16* h2n = (__bf16*)(ws + 7600384);        // 5914624 bf16 = 2957312 f
    float*  hcn = ws + 10557696;                  // 2097152 f
    float*  u   = ws + 12654848;                  // 2097152 f
    float*  bl  = ws + 14752000;                  // 655360 f
    float*  vv  = ws + 15407360;                  // 10240 f -> 15417600 f (61.7 MB)
    __bf16* uhT = (__bf16*)(ws + 375040);         // 10485760 bf16, overlays h1n (dead)

    k_t_w1<<<41, 256, 0, stream>>>(w1, w1T);
    k_t_w2b<<<800, 256, 0, stream>>>(w2, w2b);
    k_t_wcb<<<2048, 256, 0, stream>>>(wc, wcb);
    k_conv1_pool<<<dim3(42, 64), 256, 0, stream>>>(x, w1T, b1, h1n);
    k_conv2<<<dim3(10, 64), 256, 0, stream>>>(h1n, w2b, b2, h2n);
    k_convcaps<<<dim3(8, 64), 256, 0, stream>>>(h2n, wcb, bc, hcn);
    k_squash<<<dim3(64, 128), 256, 0, stream>>>(hcn, u);
    k_uhat<<<dim3(16, 10, 4), 256, 0, stream>>>(u, Wr, uhT);
    k_route_s<<<dim3(64, 10), 256, 0, stream>>>(uhT, bl, vv, out, 1, 0);
    k_route_b<<<dim3(64, 10), 256, 0, stream>>>(uhT, vv, bl, 1);
    k_route_s<<<dim3(64, 10), 256, 0, stream>>>(uhT, bl, vv, out, 0, 0);
    k_route_b<<<dim3(64, 10), 256, 0, stream>>>(uhT, vv, bl, 0);
    k_route_s<<<dim3(64, 10), 256, 0, stream>>>(uhT, bl, vv, out, 0, 1);
}

// Round 7
// 483.137 us; speedup vs baseline: 1.5005x; 1.1473x over previous
//
#include <hip/hip_runtime.h>
#include <hip/hip_bf16.h>
#include <math.h>

// ---------------------------------------------------------------------------
// GuoCapSAREncoder round 7: conv1 moved to MFMA (im2col implicit GEMM, K=81
// padded to 96). Block = (pooled row, 64-oc half, image); im2col B built in
// LDS with compile-time (kh,kw) per (kt,j); pooling via shfl_xor(1) + reg max.
// conv2/convcaps (padded-pitch LDS) and routing unchanged from round 6.
// ---------------------------------------------------------------------------

#define EPSF 1e-8f

typedef __bf16 bf16x8 __attribute__((ext_vector_type(8)));
typedef __bf16 bf16x4 __attribute__((ext_vector_type(4)));
typedef float floatx4 __attribute__((ext_vector_type(4)));

// ---- weight transposes ----------------------------------------------------
// w1[oc][81] fp32 -> w1b[12 kt][128 oc][8 j] bf16, k = kt*8+j padded to 96
__global__ __launch_bounds__(256) void k_t_w1b(const float* __restrict__ w1, __bf16* __restrict__ w1b) {
    int i = blockIdx.x * 256 + threadIdx.x;          // 12*128*8 = 12288
    if (i >= 12288) return;
    int kt = i >> 10, oc = (i >> 3) & 127, j = i & 7;
    int k = kt * 8 + j;
    w1b[i] = (__bf16)(k < 81 ? w1[oc * 81 + k] : 0.f);
}

__global__ __launch_bounds__(256) void k_t_w2b(const float* __restrict__ w2, __bf16* __restrict__ w2b) {
    int j = blockIdx.x * 256 + threadIdx.x;          // 204800
    if (j >= 204800) return;
    int khw = j / 8192, r2 = j & 8191;
    int oc = r2 >> 7, ic = r2 & 127;
    w2b[j] = (__bf16)w2[(oc * 128 + ic) * 25 + khw];
}

__global__ __launch_bounds__(256) void k_t_wcb(const float* __restrict__ wc, __bf16* __restrict__ wcb) {
    int j = blockIdx.x * 256 + threadIdx.x;          // 524288
    if (j >= 524288) return;
    int khw = j / 8192, r2 = j & 8191;
    int oc = r2 >> 6, ic = r2 & 63;
    wcb[j] = (__bf16)wc[(oc * 64 + ic) * 64 + khw];
}

// ---- conv1 9x9 + ReLU + maxpool2 via MFMA -> h1n NHWC bf16 [b][42][42][128]
// K = 81 -> 96 (3 k-steps). Block: (py, ocg of 64 oc, b).
// Bl[kt][row][pos][j]: frag reads = consecutive 16B chunks per cc (no conflict).
__global__ __launch_bounds__(256, 3) void k_conv1_mfma(const float* __restrict__ x,
                                                       const __bf16* __restrict__ w1b,
                                                       const float* __restrict__ b1,
                                                       __bf16* __restrict__ h1n) {
    __shared__ float xs[960];                        // 10 rows x 92 fp32 (+pad)
    __shared__ __bf16 Bl[18432];                     // 12kt x 2row x 96pos x 8j = 36864 B
    int py = blockIdx.x, ocg = blockIdx.y, b = blockIdx.z;
    int t = threadIdx.x;
    int lane = t & 63, w = t >> 6;
    int cc = lane & 15, q = lane >> 4;

    // stage input rows 2py..2py+9 (contiguous 920 floats)
    const float* xb = x + (size_t)b * 8464 + 2 * py * 92;
    for (int j = t; j < 920; j += 256) xs[j] = xb[j];

    // A fragments from global (L2-resident, 24 KB shared by all blocks)
    int ocA = ocg * 64 + w * 16 + cc;
    bf16x8 af[3];
#pragma unroll
    for (int ks = 0; ks < 3; ++ks)
        af[ks] = *(const bf16x8*)(w1b + ((ks * 4 + q) * 128 + ocA) * 8);

    __syncthreads();

    // im2col staging: threads 0..191 -> (row 0..1, pos 0..95)
    if (t < 192) {
        int row = t / 96, pos = t - (t / 96) * 96;
        int sbase = row * 92 + pos;
        bool pvalid = pos < 84;
#pragma unroll
        for (int kt = 0; kt < 12; ++kt) {
            bf16x8 pk;
#pragma unroll
            for (int j = 0; j < 8; ++j) {
                int k = kt * 8 + j;                  // compile-time kh,kw
                int kh = k / 9, kw = k - kh * 9;
                float v = (pvalid && k < 81) ? xs[sbase + kh * 92 + kw] : 0.f;
                pk[j] = (__bf16)v;
            }
            *(bf16x8*)(Bl + ((kt * 2 + row) * 96 + pos) * 8) = pk;
        }
    }
    __syncthreads();

    // MFMA: per wave 2 rows x 6 N-tiles x 3 k-steps
    floatx4 acc[2][6];
    const char* Bb = (const char*)Bl + cc * 16 + q * 3072;
#pragma unroll
    for (int rr = 0; rr < 2; ++rr)
#pragma unroll
        for (int n6 = 0; n6 < 6; ++n6) {
            floatx4 a = (floatx4){0.f, 0.f, 0.f, 0.f};
#pragma unroll
            for (int ks = 0; ks < 3; ++ks) {
                bf16x8 bf = *(const bf16x8*)(Bb + ks * 12288 + rr * 1536 + n6 * 256);
                a = __builtin_amdgcn_mfma_f32_16x16x32_bf16(af[ks], bf, a, 0, 0, 0);
            }
            acc[rr][n6] = a;
        }

    // epilogue: vertical max (rows) + horizontal max (shfl pairs) + bias + relu
    int oc0 = ocg * 64 + w * 16 + q * 4;
    float4 bv = *(const float4*)(b1 + oc0);
    size_t obase = (((size_t)b * 42 + py) * 42) * 128 + oc0;
#pragma unroll
    for (int n6 = 0; n6 < 6; ++n6) {
        bf16x4 pk;
#pragma unroll
        for (int r = 0; r < 4; ++r) {
            float vert = fmaxf(acc[0][n6][r], acc[1][n6][r]);
            float hz = fmaxf(vert, __shfl_xor(vert, 1, 64));
            float pooled = fmaxf(hz + ((const float*)&bv)[r], 0.f);
            pk[r] = (__bf16)pooled;
        }
        if ((cc & 1) == 0) {
            int px = n6 * 8 + (cc >> 1);
            if (px < 42)
                *(bf16x4*)(h1n + obase + (size_t)px * 128) = pk;
        }
    }
}

// ---- conv2 5x5 via MFMA: h1n NHWC bf16 -> h2n NHWC bf16 [b][38][38][64] ---
__global__ __launch_bounds__(256, 2) void k_conv2(const __bf16* __restrict__ h1n,
                                                  const __bf16* __restrict__ w2b,
                                                  const float* __restrict__ b2,
                                                  __bf16* __restrict__ h2n) {
    __shared__ __bf16 ins[22848];                    // 336 pos * 136 B = 45696 B
    int g = blockIdx.x, b = blockIdx.y;              // g in [0,10)
    int oh0 = g * 4;
    int t = threadIdx.x;
    int lane = t & 63, w = t >> 6;
    int wm = w & 1, wn = w >> 1;
    int cc = lane & 15, q = lane >> 4;

    int baseN[5], posv[5];
#pragma unroll
    for (int nt = 0; nt < 5; ++nt) {
        int p = wn * 80 + nt * 16 + cc;
        int pv = p < 152 ? p : 151;
        int r = pv / 38, c = pv - r * 38;
        posv[nt] = p;
        baseN[nt] = (r * 42 + c) * 136 + q * 16;
    }
    floatx4 acc[2][5];
#pragma unroll
    for (int mt = 0; mt < 2; ++mt)
#pragma unroll
        for (int nt = 0; nt < 5; ++nt) acc[mt][nt] = (floatx4){0.f, 0.f, 0.f, 0.f};

    int ocA0 = wm * 32 + cc;
    for (int ic0 = 0; ic0 < 128; ic0 += 64) {
        __syncthreads();
        for (int j = t; j < 2688; j += 256) {
            int lr = j / 336, rem = j - lr * 336;
            int ix = rem >> 3, sb = rem & 7;
            int rg = oh0 + lr; if (rg > 41) rg = 41;
            const uint4* src = (const uint4*)(h1n + ((((size_t)b * 42 + rg) * 42 + ix) * 128 + ic0 + sb * 8));
            int pos = lr * 42 + ix;
            *(uint4*)((char*)ins + (size_t)pos * 136 + sb * 16) = *src;
        }
        __syncthreads();
#pragma unroll
        for (int khw = 0; khw < 25; ++khw) {
            int kh = khw / 5, kw = khw - kh * 5;
            int doff = (kh * 42 + kw) * 136;
#pragma unroll
            for (int ks = 0; ks < 2; ++ks) {
                bf16x8 a0 = *(const bf16x8*)(w2b + (size_t)(khw * 64 + ocA0) * 128 + ic0 + ks * 32 + q * 8);
                bf16x8 a1 = *(const bf16x8*)(w2b + (size_t)(khw * 64 + ocA0 + 16) * 128 + ic0 + ks * 32 + q * 8);
#pragma unroll
                for (int nt = 0; nt < 5; ++nt) {
                    bf16x8 bfr = *(const bf16x8*)((char*)ins + baseN[nt] + doff + ks * 64);
                    acc[0][nt] = __builtin_amdgcn_mfma_f32_16x16x32_bf16(a0, bfr, acc[0][nt], 0, 0, 0);
                    acc[1][nt] = __builtin_amdgcn_mfma_f32_16x16x32_bf16(a1, bfr, acc[1][nt], 0, 0, 0);
                }
            }
        }
    }
#pragma unroll
    for (int mt = 0; mt < 2; ++mt) {
        int oc0 = wm * 32 + mt * 16 + q * 4;
        float4 bv = *(const float4*)(b2 + oc0);
#pragma unroll
        for (int nt = 0; nt < 5; ++nt) {
            int p = posv[nt];
            if (p < 152) {
                int r = p / 38, c = p - r * 38;
                int oh = oh0 + r;
                if (oh < 38) {
                    bf16x4 pk;
                    pk.x = (__bf16)(acc[mt][nt][0] + bv.x);
                    pk.y = (__bf16)(acc[mt][nt][1] + bv.y);
                    pk.z = (__bf16)(acc[mt][nt][2] + bv.z);
                    pk.w = (__bf16)(acc[mt][nt][3] + bv.w);
                    *(bf16x4*)(h2n + ((((size_t)b * 38 + oh) * 38 + c) * 64 + oc0)) = pk;
                }
            }
        }
    }
}

// ---- caps conv 8x8 s2 via MFMA: h2n NHWC bf16 -> hcn NHWC fp32 ------------
__global__ __launch_bounds__(256, 2) void k_convcaps(const __bf16* __restrict__ h2n,
                                                     const __bf16* __restrict__ wcb,
                                                     const float* __restrict__ bc,
                                                     float* __restrict__ hcn) {
    __shared__ __bf16 ins[13680];                    // 380 * 72 B = 27360 B
    int g = blockIdx.x, b = blockIdx.y;              // g in [0,8)
    int t = threadIdx.x;
    int lane = t & 63, w = t >> 6;
    int cc = lane & 15, q = lane >> 4;

    floatx4 acc[2][2];
#pragma unroll
    for (int mt = 0; mt < 2; ++mt)
#pragma unroll
        for (int nt = 0; nt < 2; ++nt) acc[mt][nt] = (floatx4){0.f, 0.f, 0.f, 0.f};

    int ocA = w * 32 + cc;
    int rbase = cc * 72 + q * 16;
    for (int ic0 = 0; ic0 < 64; ic0 += 32) {
        __syncthreads();
        for (int j = t; j < 1520; j += 256) {
            int r = j / 152, rem = j - r * 152;
            int c = rem >> 2, s = rem & 3;
            const uint4* src = (const uint4*)(h2n + ((((size_t)b * 38 + 4 * g + r) * 38 + c) * 64 + ic0 + s * 8));
            int X = (r * 2 + (c & 1)) * 19 + (c >> 1);
            *(uint4*)((char*)ins + X * 72 + s * 16) = *src;
        }
        __syncthreads();
#pragma unroll
        for (int khw = 0; khw < 64; ++khw) {
            int kh = khw >> 3, kw = khw & 7;
            int par = kw & 1, k2 = kw >> 1;
            bf16x8 a0 = *(const bf16x8*)(wcb + (size_t)(khw * 128 + ocA) * 64 + ic0 + q * 8);
            bf16x8 a1 = *(const bf16x8*)(wcb + (size_t)(khw * 128 + ocA + 16) * 64 + ic0 + q * 8);
#pragma unroll
            for (int nt = 0; nt < 2; ++nt) {
                int doff = (((2 * nt + kh) * 2 + par) * 19 + k2) * 72;
                bf16x8 bfr = *(const bf16x8*)((char*)ins + rbase + doff);
                acc[0][nt] = __builtin_amdgcn_mfma_f32_16x16x32_bf16(a0, bfr, acc[0][nt], 0, 0, 0);
                acc[1][nt] = __builtin_amdgcn_mfma_f32_16x16x32_bf16(a1, bfr, acc[1][nt], 0, 0, 0);
            }
        }
    }
#pragma unroll
    for (int mt = 0; mt < 2; ++mt) {
        int oc0 = w * 32 + mt * 16 + q * 4;
        float4 bv = *(const float4*)(bc + oc0);
#pragma unroll
        for (int nt = 0; nt < 2; ++nt) {
            int oh = 2 * g + nt, ow = cc;
            float4 st;
            st.x = acc[mt][nt][0] + bv.x;
            st.y = acc[mt][nt][1] + bv.y;
            st.z = acc[mt][nt][2] + bv.z;
            st.w = acc[mt][nt][3] + bv.w;
            *(float4*)(hcn + (((size_t)b * 256 + oh * 16 + ow) * 128 + oc0)) = st;
        }
    }
}

// ---- primary-capsule reorder + squash: hcn NHWC -> u:[64,1024,32] ---------
__global__ __launch_bounds__(256) void k_squash(const float* __restrict__ hcn,
                                                float* __restrict__ u) {
    int b = blockIdx.x, capg = blockIdx.y;
    int t = threadIdx.x;
    int capl = t >> 5, i = t & 31;
    int cap = capg * 8 + capl;
    int ct = cap >> 8, rem = cap & 255;
    float val = hcn[((size_t)b * 256 + rem) * 128 + ct * 32 + i];
    float s = val * val;
#pragma unroll
    for (int off = 1; off < 32; off <<= 1) s += __shfl_xor(s, off, 64);
    float scale = (s / (1.f + s)) / sqrtf(s + EPSF);
    u[((size_t)b * 1024 + cap) * 32 + i] = val * scale;
}

// ---- u_hat: u:[64,1024,32] Wr:[1024,10,16,32] -> uhT bf16 [b][t][o][p] ----
__global__ __launch_bounds__(256) void k_uhat(const float* __restrict__ u,
                                              const float* __restrict__ Wr,
                                              __bf16* __restrict__ uhT) {
    int pt = blockIdx.x;   // 16 tiles of 64 p
    int ts = blockIdx.y;   // 10
    int bz = blockIdx.z;   // 4 groups of 16 b
    int t = threadIdx.x;
    int p = pt * 64 + (t & 63);
    int q = t >> 6;
    for (int b = bz * 16 + q; b < bz * 16 + 16; b += 4) {
        float4 uu[8];
        const float4* up = (const float4*)(u + ((size_t)b * 1024 + p) * 32);
#pragma unroll
        for (int j = 0; j < 8; ++j) uu[j] = up[j];
#pragma unroll
        for (int o = 0; o < 16; ++o) {
            const float4* wp = (const float4*)(Wr + (((size_t)p * 10 + ts) * 16 + o) * 32);
            float4 a = {0.f, 0.f, 0.f, 0.f};
#pragma unroll
            for (int j = 0; j < 8; ++j) {
                float4 w4 = wp[j];
                a.x = fmaf(uu[j].x, w4.x, a.x);
                a.y = fmaf(uu[j].y, w4.y, a.y);
                a.z = fmaf(uu[j].z, w4.z, a.z);
                a.w = fmaf(uu[j].w, w4.w, a.w);
            }
            uhT[(((size_t)b * 10 + ts) * 16 + o) * 1024 + p] = (__bf16)((a.x + a.y) + (a.z + a.w));
        }
    }
}

// ---- routing: s = sum_p softmax(bl)_pt * u_hat ; v = squash(s) ------------
__global__ __launch_bounds__(256) void k_route_s(const __bf16* __restrict__ uhT,
                                                 const float* __restrict__ bl,
                                                 float* __restrict__ vout,
                                                 float* __restrict__ out,
                                                 int first, int last) {
    __shared__ float sred[4][16];
    int b = blockIdx.x, tt = blockIdx.y;
    int t = threadIdx.x;
    float acc[16];
#pragma unroll
    for (int o = 0; o < 16; ++o) acc[o] = 0.f;
    const float* blb = bl + b * 10240;
    const __bf16* uhb = uhT + ((size_t)b * 10 + tt) * 16384;
    for (int p = t; p < 1024; p += 256) {
        float c;
        if (first) {
            c = 0.1f;
        } else {
            float den = 0.f, et = 0.f;
#pragma unroll
            for (int tp = 0; tp < 10; ++tp) {
                float e = expf(blb[tp * 1024 + p]);
                den += e;
                if (tp == tt) et = e;
            }
            c = et / den;
        }
#pragma unroll
        for (int o = 0; o < 16; ++o)
            acc[o] = fmaf(c, (float)uhb[o * 1024 + p], acc[o]);
    }
    int lane = t & 63, wid = t >> 6;
#pragma unroll
    for (int o = 0; o < 16; ++o) {
        float v = acc[o];
#pragma unroll
        for (int off = 32; off >= 1; off >>= 1) v += __shfl_xor(v, off, 64);
        if (lane == 0) sred[wid][o] = v;
    }
    __syncthreads();
    if (t < 16) {
        float s = (sred[0][t] + sred[1][t]) + (sred[2][t] + sred[3][t]);
        float n2 = s * s;
#pragma unroll
        for (int off = 1; off < 16; off <<= 1) n2 += __shfl_xor(n2, off, 16);
        float scale = (n2 / (1.f + n2)) / sqrtf(n2 + EPSF);
        vout[(b * 10 + tt) * 16 + t] = s * scale;
        if (last && t == 0) {
            float sv2 = n2 * scale * scale;
            out[b * 10 + tt] = sqrtf(sv2 + EPSF);
        }
    }
}

// ---- routing: bl (+)= sum_o u_hat * v -------------------------------------
__global__ __launch_bounds__(256) void k_route_b(const __bf16* __restrict__ uhT,
                                                 const float* __restrict__ vv,
                                                 float* __restrict__ bl,
                                                 int first) {
    __shared__ float vs[16];
    int b = blockIdx.x, tt = blockIdx.y;
    int t = threadIdx.x;
    if (t < 16) vs[t] = vv[(b * 10 + tt) * 16 + t];
    __syncthreads();
    const __bf16* uhb = uhT + ((size_t)b * 10 + tt) * 16384;
    float* blb = bl + (b * 10 + tt) * 1024;
    for (int p = t; p < 1024; p += 256) {
        float d = 0.f;
#pragma unroll
        for (int o = 0; o < 16; ++o) d = fmaf((float)uhb[o * 1024 + p], vs[o], d);
        blb[p] = first ? d : (blb[p] + d);
    }
}

// ---------------------------------------------------------------------------
extern "C" void kernel_launch(void* const* d_in, const int* in_sizes, int n_in,
                              void* d_out, int out_size, void* d_ws, size_t ws_size,
                              hipStream_t stream) {
    const float* x  = (const float*)d_in[0];
    const float* w1 = (const float*)d_in[1];
    const float* b1 = (const float*)d_in[2];
    const float* w2 = (const float*)d_in[3];
    const float* b2 = (const float*)d_in[4];
    const float* wc = (const float*)d_in[5];
    const float* bc = (const float*)d_in[6];
    const float* Wr = (const float*)d_in[7];
    float* out = (float*)d_out;
    float* ws  = (float*)d_ws;

    // workspace layout (float offsets)
    __bf16* w2b = (__bf16*)(ws);                  // 204800 bf16 = 102400 f
    __bf16* wcb = (__bf16*)(ws + 102400);         // 524288 bf16 = 262144 f
    __bf16* w1b = (__bf16*)(ws + 364544);         // 12288 bf16 = 6144 f (pad 10496)
    __bf16* h1n = (__bf16*)(ws + 375040);         // 14450688 bf16 = 7225344 f
    __bf16* h2n = (__bf16*)(ws + 7600384);        // 5914624 bf16 = 2957312 f
    float*  hcn = ws + 10557696;                  // 2097152 f
    float*  u   = ws + 12654848;                  // 2097152 f
    float*  bl  = ws + 14752000;                  // 655360 f
    float*  vv  = ws + 15407360;                  // 10240 f -> 15417600 f (61.7 MB)
    __bf16* uhT = (__bf16*)(ws + 375040);         // 10485760 bf16, overlays h1n (dead)

    k_t_w1b<<<48, 256, 0, stream>>>(w1, w1b);
    k_t_w2b<<<800, 256, 0, stream>>>(w2, w2b);
    k_t_wcb<<<2048, 256, 0, stream>>>(wc, wcb);
    k_conv1_mfma<<<dim3(42, 2, 64), 256, 0, stream>>>(x, w1b, b1, h1n);
    k_conv2<<<dim3(10, 64), 256, 0, stream>>>(h1n, w2b, b2, h2n);
    k_convcaps<<<dim3(8, 64), 256, 0, stream>>>(h2n, wcb, bc, hcn);
    k_squash<<<dim3(64, 128), 256, 0, stream>>>(hcn, u);
    k_uhat<<<dim3(16, 10, 4), 256, 0, stream>>>(u, Wr, uhT);
    k_route_s<<<dim3(64, 10), 256, 0, stream>>>(uhT, bl, vv, out, 1, 0);
    k_route_b<<<dim3(64, 10), 256, 0, stream>>>(uhT, vv, bl, 1);
    k_route_s<<<dim3(64, 10), 256, 0, stream>>>(uhT, bl, vv, out, 0, 0);
    k_route_b<<<dim3(64, 10), 256, 0, stream>>>(uhT, vv, bl, 0);
    k_route_s<<<dim3(64, 10), 256, 0, stream>>>(uhT, bl, vv, out, 0, 1);
}